// Round 1
// baseline (92.399 us; speedup 1.0000x reference)
//
#include <hip/hip_runtime.h>
#include <math.h>

#define NUM_VIEW 300
#define BSZ 256

// B=8, N=500000, S=4096 fixed by setup_inputs()
#define BB 8
#define NN 500000
#define SS 4096

__global__ __launch_bounds__(BSZ) void normal_policy_kernel(
    const float* __restrict__ cloud_normals,   // [B,N,3] f32
    const int*   __restrict__ idxs,            // [B,S] i32
    float*       __restrict__ out)             // flat: [B*S] idx | [B*S*3] vp_xyz | [B*S*9] vp_rot
{
    // ---- stage view codebook in LDS (computed in f64 to match numpy, cast f32) ----
    __shared__ float sv[NUM_VIEW][4];  // x,y,z,|v|^2
    const double PHI = (sqrt(5.0) - 1.0) / 2.0;
    for (int v = threadIdx.x; v < NUM_VIEW; v += BSZ) {
        double i  = (double)v;
        double zi = (2.0 * i + 1.0) / (double)NUM_VIEW - 1.0;
        double rr = 1.0 - zi * zi;
        if (rr < 0.0) rr = 0.0;
        double r  = sqrt(rr);
        double a  = 2.0 * i * M_PI * PHI;
        float xf = (float)(r * cos(a));
        float yf = (float)(r * sin(a));
        float zf = (float)zi;
        sv[v][0] = xf;
        sv[v][1] = yf;
        sv[v][2] = zf;
        sv[v][3] = (float)((double)xf * xf + (double)yf * yf + (double)zf * zf);
    }
    __syncthreads();

    const int total = BB * SS;
    int p = blockIdx.x * BSZ + threadIdx.x;
    if (p >= total) return;
    int b = p >> 12;            // p / 4096
    // gather normal
    int idx = idxs[p];
    const float* nptr = cloud_normals + ((size_t)b * NN + (size_t)idx) * 3;
    float nx = nptr[0], ny = nptr[1], nz = nptr[2];

    // ---- 1-NN over 300 views (f64 to track the f64 numpy reference) ----
    double dx = (double)nx, dy = (double)ny, dz = (double)nz;
    double xx = dx * dx + dy * dy + dz * dz;
    double best = 1.0e300;
    int bi = 0;
    #pragma unroll 4
    for (int v = 0; v < NUM_VIEW; ++v) {
        double vx = (double)sv[v][0];
        double vy = (double)sv[v][1];
        double vz = (double)sv[v][2];
        double vv = (double)sv[v][3];
        double d2 = xx - 2.0 * (dx * vx + dy * vy + dz * vz) + vv;
        if (d2 < best) { best = d2; bi = v; }   // strict < keeps first index on ties
    }

    // ---- rotation matrix: towards = -n, angle = 0 -> R = [ax_n | ay_n | az] cols ----
    // ax = -n ; ay = [-ax.y, ax.x, 0] = [n.y, -n.x, 0] (exact negations)
    double axx = -dx, axy = -dy, axz = -dz;
    double ayx = dy, ayy = -dx, ayz = 0.0;
    if (ayx == 0.0 && ayy == 0.0) { ayx = 0.0; ayy = 1.0; ayz = 0.0; }  // degenerate
    double na = sqrt(axx * axx + axy * axy + axz * axz);
    axx /= na; axy /= na; axz /= na;
    double nb = sqrt(ayx * ayx + ayy * ayy + ayz * ayz);
    ayx /= nb; ayy /= nb; ayz /= nb;
    // az = ax x ay
    double azx = axy * ayz - axz * ayy;
    double azy = axz * ayx - axx * ayz;
    double azz = axx * ayy - axy * ayx;

    // ---- stores ----
    out[p] = (float)bi;
    float* o_xyz = out + total;
    o_xyz[3 * p + 0] = nx;
    o_xyz[3 * p + 1] = ny;
    o_xyz[3 * p + 2] = nz;
    float* o_rot = out + total * 4;  // total + total*3
    // row-major 3x3 with columns ax, ay, az
    o_rot[9 * p + 0] = (float)axx;
    o_rot[9 * p + 1] = (float)ayx;
    o_rot[9 * p + 2] = (float)azx;
    o_rot[9 * p + 3] = (float)axy;
    o_rot[9 * p + 4] = (float)ayy;
    o_rot[9 * p + 5] = (float)azy;
    o_rot[9 * p + 6] = (float)axz;
    o_rot[9 * p + 7] = (float)ayz;
    o_rot[9 * p + 8] = (float)azz;
}

extern "C" void kernel_launch(void* const* d_in, const int* in_sizes, int n_in,
                              void* d_out, int out_size, void* d_ws, size_t ws_size,
                              hipStream_t stream) {
    const float* cloud_normals = (const float*)d_in[0];
    const int*   idxs          = (const int*)d_in[1];
    float*       out           = (float*)d_out;
    const int total = BB * SS;  // 32768
    const int blocks = (total + BSZ - 1) / BSZ;  // 128
    hipLaunchKernelGGL(normal_policy_kernel, dim3(blocks), dim3(BSZ), 0, stream,
                       cloud_normals, idxs, out);
}

// Round 2
// 85.761 us; speedup vs baseline: 1.0774x; 1.0774x over previous
//
#include <hip/hip_runtime.h>
#include <math.h>

#define NUM_VIEW 300
#define BSZ 256

// B=8, N=500000, S=4096 fixed by setup_inputs()
#define BB 8
#define NN 500000
#define SS 4096
#define TOTAL (BB * SS)          // 32768 points
#define LANES_PER_PT 4
#define VIEWS_PER_LANE 75        // 300 / 4

// ---- kernel A: compute the 300-view Fibonacci codebook once (fp64, cast f32
// to bit-match numpy's float64->float32 path), store to workspace ----
__global__ __launch_bounds__(320) void codebook_kernel(float4* __restrict__ cb) {
    int v = threadIdx.x;
    if (v >= NUM_VIEW) return;
    const double PHI = (sqrt(5.0) - 1.0) / 2.0;
    double i  = (double)v;
    double zi = (2.0 * i + 1.0) / (double)NUM_VIEW - 1.0;
    double rr = 1.0 - zi * zi;
    if (rr < 0.0) rr = 0.0;
    double r  = sqrt(rr);
    double a  = 2.0 * i * M_PI * PHI;
    float xf = (float)(r * cos(a));
    float yf = (float)(r * sin(a));
    float zf = (float)zi;
    float vv = (float)((double)xf * xf + (double)yf * yf + (double)zf * zf);
    cb[v] = make_float4(xf, yf, zf, vv);
}

// ---- kernel B: gather + 1-NN (4 lanes/point, 75 views each) + rotation ----
__global__ __launch_bounds__(BSZ) void normal_policy_kernel(
    const float* __restrict__ cloud_normals,   // [B,N,3] f32
    const int*   __restrict__ idxs,            // [B,S] i32
    const float4* __restrict__ cb,             // [300] x,y,z,|v|^2
    float*       __restrict__ out)             // flat: [B*S] idx | [B*S*3] xyz | [B*S*9] rot
{
    __shared__ float sv[NUM_VIEW][4];
    for (int v = threadIdx.x; v < NUM_VIEW; v += BSZ) {
        float4 c = cb[v];
        sv[v][0] = c.x; sv[v][1] = c.y; sv[v][2] = c.z; sv[v][3] = c.w;
    }
    __syncthreads();

    int t = blockIdx.x * BSZ + threadIdx.x;   // 131072 threads, exact cover
    int p = t >> 2;                           // point id
    int r = t & 3;                            // lane role within quad
    int b = p >> 12;                          // batch (p / 4096)

    int idx = idxs[p];
    const float* nptr = cloud_normals + ((size_t)b * NN + (size_t)idx) * 3;
    float nx = nptr[0], ny = nptr[1], nz = nptr[2];

    // ---- partial 1-NN over this lane's 75 views (fp64, matches np f64 ref) ----
    double dx = (double)nx, dy = (double)ny, dz = (double)nz;
    double xx = dx * dx + dy * dy + dz * dz;
    double best = 1.0e300;
    int bi = 0;
    int vbase = r * VIEWS_PER_LANE;
    #pragma unroll 5
    for (int j = 0; j < VIEWS_PER_LANE; ++j) {
        int v = vbase + j;
        double vx = (double)sv[v][0];
        double vy = (double)sv[v][1];
        double vz = (double)sv[v][2];
        double vv = (double)sv[v][3];
        double d2 = xx - 2.0 * (dx * vx + dy * vy + dz * vz) + vv;
        if (d2 < best) { best = d2; bi = v; }   // strict <: first index wins
    }

    // ---- quad reduction (xor 1, 2) with lowest-index tie-break ----
    #pragma unroll
    for (int m = 1; m <= 2; m <<= 1) {
        double ob = __shfl_xor(best, m, 64);
        int    oi = __shfl_xor(bi,   m, 64);
        if (ob < best || (ob == best && oi < bi)) { best = ob; bi = oi; }
    }

    if (r == 0) {
        // rotation: towards = -n, angle = 0 -> R = [ax_n | ay_n | az] columns
        double axx = -dx, axy = -dy, axz = -dz;
        double ayx = dy, ayy = -dx, ayz = 0.0;
        if (ayx == 0.0 && ayy == 0.0) { ayx = 0.0; ayy = 1.0; ayz = 0.0; }
        double ia = 1.0 / sqrt(axx * axx + axy * axy + axz * axz);
        axx *= ia; axy *= ia; axz *= ia;
        double ib = 1.0 / sqrt(ayx * ayx + ayy * ayy + ayz * ayz);
        ayx *= ib; ayy *= ib; ayz *= ib;
        double azx = axy * ayz - axz * ayy;
        double azy = axz * ayx - axx * ayz;
        double azz = axx * ayy - axy * ayx;

        out[p] = (float)bi;
        float* o_xyz = out + TOTAL;
        o_xyz[3 * p + 0] = nx;
        o_xyz[3 * p + 1] = ny;
        o_xyz[3 * p + 2] = nz;
        float* o_rot = out + TOTAL * 4;
        o_rot[9 * p + 0] = (float)axx;
        o_rot[9 * p + 1] = (float)ayx;
        o_rot[9 * p + 2] = (float)azx;
        o_rot[9 * p + 3] = (float)axy;
        o_rot[9 * p + 4] = (float)ayy;
        o_rot[9 * p + 5] = (float)azy;
        o_rot[9 * p + 6] = (float)axz;
        o_rot[9 * p + 7] = (float)ayz;
        o_rot[9 * p + 8] = (float)azz;
    }
}

extern "C" void kernel_launch(void* const* d_in, const int* in_sizes, int n_in,
                              void* d_out, int out_size, void* d_ws, size_t ws_size,
                              hipStream_t stream) {
    const float* cloud_normals = (const float*)d_in[0];
    const int*   idxs          = (const int*)d_in[1];
    float*       out           = (float*)d_out;
    float4*      cb            = (float4*)d_ws;

    hipLaunchKernelGGL(codebook_kernel, dim3(1), dim3(320), 0, stream, cb);

    const int threads = TOTAL * LANES_PER_PT;        // 131072
    const int blocks  = threads / BSZ;               // 512
    hipLaunchKernelGGL(normal_policy_kernel, dim3(blocks), dim3(BSZ), 0, stream,
                       cloud_normals, idxs, cb, out);
}